// Round 7
// baseline (45.472 us; speedup 1.0000x reference)
//
#include <hip/hip_runtime.h>
#include <hip/hip_bf16.h>

#define N_ATOMS 2048
#define C_DIM   128
#define C_PAIR  16
#define BLK_K   128
#define LN_EPS  1e-5f

typedef float f32x4 __attribute__((ext_vector_type(4)));
typedef short s16x8 __attribute__((ext_vector_type(8)));

__device__ __forceinline__ float bf_lo(unsigned int p) {
    union { unsigned int i; float f; } u; u.i = p << 16; return u.f;
}
__device__ __forceinline__ float bf_hi(unsigned int p) {
    union { unsigned int i; float f; } u; u.i = p & 0xffff0000u; return u.f;
}
__device__ __forceinline__ float bf2f(unsigned short s) {
    union { unsigned int i; float f; } u; u.i = ((unsigned int)s) << 16; return u.f;
}
__device__ __forceinline__ unsigned short f2bf(float f) {
    union { float f; unsigned int i; } u; u.f = f;
    const unsigned int r = u.i + 0x7fffu + ((u.i >> 16) & 1u);  // RNE
    return (unsigned short)(r >> 16);
}

// A-fragment read from swizzled bf16 LDS tile [16][rowBytes/2].
__device__ __forceinline__ s16x8 lda_frag(const unsigned short* base,
                                          int rowBytes, int kstep, int lane) {
    const int m    = lane & 15;
    const int koff = kstep * 64 + ((lane >> 4) << 4);
    const int addr = m * rowBytes + (koff ^ ((m & 7) << 4));
    return *reinterpret_cast<const s16x8*>(
        reinterpret_cast<const char*>(base) + addr);
}

// ---------------------------------------------------------------------------
// Weight packing: W [Nout][K] f32 row-major -> bf16 B-fragment stream.
// units: Wout 32 (8x4), W1 128 (32x4), W2 128 (8x16)  => 288 total
// ---------------------------------------------------------------------------
__device__ void pack_unit(int u, int lane,
                          const float* __restrict__ Wout,
                          const float* __restrict__ W1,
                          const float* __restrict__ W2,
                          unsigned short* __restrict__ WoutP,
                          unsigned short* __restrict__ W1P,
                          unsigned short* __restrict__ W2P)
{
    const float* W; unsigned short* P; int K, local;
    if (u < 32)       { W = Wout; P = WoutP; K = 128; local = u; }
    else if (u < 160) { W = W1;   P = W1P;   K = 128; local = u - 32; }
    else              { W = W2;   P = W2P;   K = 512; local = u - 160; }
    const int ksteps = K >> 5;
    const int ntile  = local / ksteps;
    const int kstep  = local - ntile * ksteps;
    const int n  = ntile * 16 + (lane & 15);
    const int k0 = kstep * 32 + ((lane >> 4) << 3);
    const float4* src = reinterpret_cast<const float4*>(W + (size_t)n * K + k0);
    const float4 a = src[0], b = src[1];
    s16x8 o;
    o[0] = (short)f2bf(a.x); o[1] = (short)f2bf(a.y);
    o[2] = (short)f2bf(a.z); o[3] = (short)f2bf(a.w);
    o[4] = (short)f2bf(b.x); o[5] = (short)f2bf(b.y);
    o[6] = (short)f2bf(b.z); o[7] = (short)f2bf(b.w);
    reinterpret_cast<s16x8*>(P)[local * 64 + lane] = o;
}

// ---------------------------------------------------------------------------
// K1: LayerNorm(x) -> swizzled bf16 LDS; q/k/v via MFMA, weight B-fragments
// loaded directly from f32 global. 512 threads, 16 rows/block, grid 128.
// (unchanged from R5)
// ---------------------------------------------------------------------------
__global__ __launch_bounds__(512) void ln_qkv_kernel(
    const float* __restrict__ x,
    const float* __restrict__ Wq, const float* __restrict__ Wk,
    const float* __restrict__ Wv,
    const float* __restrict__ Wout, const float* __restrict__ W1,
    const float* __restrict__ W2,
    float* __restrict__ q,
    unsigned short* __restrict__ kb, unsigned short* __restrict__ vb,
    unsigned short* __restrict__ WoutP, unsigned short* __restrict__ W1P,
    unsigned short* __restrict__ W2P)
{
    __shared__ __align__(16) unsigned short hB[16][128];  // 4 KB swizzled bf16
    const int t = threadIdx.x;
    const int bid = blockIdx.x;
    const int row0 = bid * 16;

    if (t < 64)       pack_unit(bid * 2,     t,       Wout, W1, W2, WoutP, W1P, W2P);
    else if (t < 128) pack_unit(bid * 2 + 1, t - 64,  Wout, W1, W2, WoutP, W1P, W2P);
    else if (t < 192 && bid < 32)
                      pack_unit(256 + bid,   t - 128, Wout, W1, W2, WoutP, W1P, W2P);

    {
        const int r = t >> 5, l = t & 31;
        const float4 xv = reinterpret_cast<const float4*>(
            x + (size_t)(row0 + r) * C_DIM)[l];
        float s  = xv.x + xv.y + xv.z + xv.w;
        float ss = xv.x*xv.x + xv.y*xv.y + xv.z*xv.z + xv.w*xv.w;
        #pragma unroll
        for (int m = 16; m >= 1; m >>= 1) {
            s  += __shfl_xor(s,  m);
            ss += __shfl_xor(ss, m);
        }
        const float mu  = s * (1.0f / 128.0f);
        const float var = ss * (1.0f / 128.0f) - mu * mu;
        const float inv = rsqrtf(var + LN_EPS);
        union { unsigned long long u64; unsigned short u16[4]; } pk;
        pk.u16[0] = f2bf((xv.x - mu) * inv);
        pk.u16[1] = f2bf((xv.y - mu) * inv);
        pk.u16[2] = f2bf((xv.z - mu) * inv);
        pk.u16[3] = f2bf((xv.w - mu) * inv);
        *reinterpret_cast<unsigned long long*>(
            reinterpret_cast<char*>(&hB[0][0]) +
            r * 256 + ((l * 8) ^ ((r & 7) << 4))) = pk.u64;
    }
    __syncthreads();

    {
        const int wv = t >> 6, lane = t & 63;
        s16x8 afr[4];
        #pragma unroll
        for (int ks = 0; ks < 4; ++ks) afr[ks] = lda_frag(&hB[0][0], 256, ks, lane);

        const int n = wv * 16 + (lane & 15);
        #pragma unroll
        for (int p = 0; p < 3; ++p) {
            const float* W = (p == 0) ? Wq : (p == 1) ? Wk : Wv;
            f32x4 acc = {0.f, 0.f, 0.f, 0.f};
            #pragma unroll
            for (int ks = 0; ks < 4; ++ks) {
                const int k0 = ks * 32 + ((lane >> 4) << 3);
                const float4* src = reinterpret_cast<const float4*>(
                    W + (size_t)n * C_DIM + k0);
                const float4 a = src[0], b = src[1];
                s16x8 bfr;
                bfr[0] = (short)f2bf(a.x); bfr[1] = (short)f2bf(a.y);
                bfr[2] = (short)f2bf(a.z); bfr[3] = (short)f2bf(a.w);
                bfr[4] = (short)f2bf(b.x); bfr[5] = (short)f2bf(b.y);
                bfr[6] = (short)f2bf(b.z); bfr[7] = (short)f2bf(b.w);
                acc = __builtin_amdgcn_mfma_f32_16x16x32_bf16(afr[ks], bfr, acc, 0, 0, 0);
            }
            #pragma unroll
            for (int ii = 0; ii < 4; ++ii) {
                const int m = ((lane >> 4) << 2) + ii;   // 0..15
                const size_t off = (size_t)(row0 + m) * C_DIM + n;
                if (p == 0)      q[off]  = acc[ii];
                else if (p == 1) kb[off] = f2bf(acc[ii]);
                else             vb[off] = f2bf(acc[ii]);
            }
        }
    }
}

// ---------------------------------------------------------------------------
// K2: fused attention + proj/LN/MLP. 512 threads, 4 query rows per block,
// grid 512 => 2+ blocks/CU so gather-stall phases of one block overlap
// compute phases of the other (barrier drain no longer serializes the CU).
// ---------------------------------------------------------------------------
__global__ __launch_bounds__(512, 4) void attn_mlp_kernel(
    const float* __restrict__ q, const unsigned short* __restrict__ kb,
    const unsigned short* __restrict__ vb, const float* __restrict__ pair,
    const int*  __restrict__ bidx, const float* __restrict__ Wb,
    const float* __restrict__ x,
    const unsigned short* __restrict__ WoutP,
    const unsigned short* __restrict__ W1P, const float* __restrict__ b1,
    const unsigned short* __restrict__ W2P, const float* __restrict__ b2,
    float* __restrict__ out)
{
    __shared__ __align__(16) float qS[4][128];            // 2 KB
    __shared__ __align__(16) int   idxS[4][128];          // 2 KB
    __shared__ __align__(16) float S[4][4][128];          // 8 KB
    __shared__ __align__(16) float ys[4][128];            // 2 KB  x1 rows
    __shared__ __align__(16) unsigned short aoB[16][128]; // 4 KB  bf16 swz
    __shared__ __align__(16) unsigned short h2B[16][128]; // 4 KB  bf16 swz
    __shared__ __align__(16) unsigned short gsB[16][512]; // 16 KB bf16 swz

    const int t = threadIdx.x;
    const int row0 = blockIdx.x * 4;
    const int r = t >> 7;          // local row 0..3
    const int u = t & 127;         // key slot / dim
    const int row = row0 + r;
    const int wv = t >> 6, lane = t & 63;

    // --- A: stage q, idx, x; zero MFMA pad rows; issue pair gather ---
    const int j = bidx[(size_t)row * BLK_K + u];
    idxS[r][u] = j;
    qS[r][u] = q[(size_t)row * C_DIM + u];
    if (t < 128) {
        const int r2 = t >> 5, l = t & 31;
        const float4 xv = reinterpret_cast<const float4*>(
            x + (size_t)(row0 + r2) * C_DIM)[l];
        *reinterpret_cast<float4*>(&ys[r2][l * 4]) = xv;
    }
    {
        const uint4 z = {0,0,0,0};
        #pragma unroll
        for (int s = t; s < 192; s += 512)
            reinterpret_cast<uint4*>(&aoB[4][0])[s] = z;   // rows 4..15
        #pragma unroll
        for (int s = t; s < 192; s += 512)
            reinterpret_cast<uint4*>(&h2B[4][0])[s] = z;   // rows 4..15
        for (int s = t; s < 768; s += 512)
            reinterpret_cast<uint4*>(&gsB[4][0])[s] = z;   // rows 4..15
    }
    const f32x4* pr = reinterpret_cast<const f32x4*>(
        pair + ((size_t)row * N_ATOMS + (size_t)j) * C_PAIR);
    const f32x4 p0 = __builtin_nontemporal_load(pr + 0);
    const f32x4 p1 = __builtin_nontemporal_load(pr + 1);
    const f32x4 p2 = __builtin_nontemporal_load(pr + 2);
    const f32x4 p3 = __builtin_nontemporal_load(pr + 3);
    __syncthreads();

    // --- scores: thread (r, u) dots q row r with bf16 k[j] for 4 heads ---
    {
        const uint4* kr = reinterpret_cast<const uint4*>(kb + (size_t)j * C_DIM);
        const float4* q4 = reinterpret_cast<const float4*>(&qS[r][0]);
        float sc[4];
        #pragma unroll
        for (int h = 0; h < 4; ++h) {
            float a = 0.f;
            #pragma unroll
            for (int d = 0; d < 4; ++d) {
                const uint4  kk = kr[h * 4 + d];
                const float4 qa = q4[h * 8 + d * 2];
                const float4 qc = q4[h * 8 + d * 2 + 1];
                a += bf_lo(kk.x)*qa.x + bf_hi(kk.x)*qa.y
                   + bf_lo(kk.y)*qa.z + bf_hi(kk.y)*qa.w;
                a += bf_lo(kk.z)*qc.x + bf_hi(kk.z)*qc.y
                   + bf_lo(kk.w)*qc.z + bf_hi(kk.w)*qc.w;
            }
            sc[h] = a;
        }
        const float pm = (p0.x+p0.y+p0.z+p0.w + p1.x+p1.y+p1.z+p1.w +
                          p2.x+p2.y+p2.z+p2.w + p3.x+p3.y+p3.z+p3.w) * (1.0f/16.0f);
        const float scale = 0.17677669529663687f;  // 1/sqrt(32)
        #pragma unroll
        for (int h = 0; h < 4; ++h)
            S[r][h][u] = sc[h] * scale + pm * Wb[h];
    }
    __syncthreads();

    // --- softmax per (row, head): 32 lanes per head ---
    {
        const int g = u >> 5, l = u & 31;
        const float v0 = S[r][g][l],      v1 = S[r][g][l + 32],
                    v2 = S[r][g][l + 64], v3 = S[r][g][l + 96];
        float mx = fmaxf(fmaxf(v0, v1), fmaxf(v2, v3));
        #pragma unroll
        for (int m = 16; m >= 1; m >>= 1) mx = fmaxf(mx, __shfl_xor(mx, m));
        const float e0 = __expf(v0 - mx), e1 = __expf(v1 - mx),
                    e2 = __expf(v2 - mx), e3 = __expf(v3 - mx);
        float sm = e0 + e1 + e2 + e3;
        #pragma unroll
        for (int m = 16; m >= 1; m >>= 1) sm += __shfl_xor(sm, m);
        const float rs = 1.0f / sm;
        S[r][g][l]      = e0 * rs;
        S[r][g][l + 32] = e1 * rs;
        S[r][g][l + 64] = e2 * rs;
        S[r][g][l + 96] = e3 * rs;
    }
    __syncthreads();

    // --- PV: thread (r, dim u); coalesced bf16 v; write swizzled aoB ---
    {
        const int hh = u >> 5;
        const float4* Sv = reinterpret_cast<const float4*>(&S[r][hh][0]);
        const int4*   iv = reinterpret_cast<const int4*>(&idxS[r][0]);
        float acc = 0.f;
        #pragma unroll 8
        for (int bq = 0; bq < 32; ++bq) {
            const float4 s4 = Sv[bq];
            const int4   j4 = iv[bq];
            acc += s4.x * bf2f(vb[(size_t)j4.x * C_DIM + u]);
            acc += s4.y * bf2f(vb[(size_t)j4.y * C_DIM + u]);
            acc += s4.z * bf2f(vb[(size_t)j4.z * C_DIM + u]);
            acc += s4.w * bf2f(vb[(size_t)j4.w * C_DIM + u]);
        }
        *reinterpret_cast<unsigned short*>(
            reinterpret_cast<char*>(&aoB[0][0]) +
            r * 256 + (((u * 2)) ^ ((r & 7) << 4))) = f2bf(acc);
    }
    __syncthreads();

    // --- P: x1 = x + ao @ Wout.T  (8 waves, wave w -> col tile w) ---
    {
        f32x4 acc = {0.f, 0.f, 0.f, 0.f};
        const s16x8* Bp = reinterpret_cast<const s16x8*>(WoutP);
        #pragma unroll
        for (int ks = 0; ks < 4; ++ks) {
            const s16x8 a = lda_frag(&aoB[0][0], 256, ks, lane);
            const s16x8 b = Bp[(wv * 4 + ks) * 64 + lane];
            acc = __builtin_amdgcn_mfma_f32_16x16x32_bf16(a, b, acc, 0, 0, 0);
        }
        if (lane < 32) {
            const int c = wv * 16 + (lane & 15);
            #pragma unroll
            for (int i = 0; i < 4; ++i) {
                const int m = ((lane >> 4) << 2) + i;   // 0..7
                if (m < 4) ys[m][c] += acc[i];
            }
        }
    }
    __syncthreads();

    // --- LN: h2 = LayerNorm(x1) -> swizzled bf16 ---
    if (t < 128) {
        const int rr = t >> 5, l = t & 31;
        const float4 yv = *reinterpret_cast<const float4*>(&ys[rr][l * 4]);
        float s  = yv.x + yv.y + yv.z + yv.w;
        float ss = yv.x*yv.x + yv.y*yv.y + yv.z*yv.z + yv.w*yv.w;
        #pragma unroll
        for (int m = 16; m >= 1; m >>= 1) {
            s  += __shfl_xor(s,  m);
            ss += __shfl_xor(ss, m);
        }
        const float mu  = s * (1.0f / 128.0f);
        const float var = ss * (1.0f / 128.0f) - mu * mu;
        const float inv = rsqrtf(var + LN_EPS);
        union { unsigned long long u64; unsigned short u16[4]; } pk;
        pk.u16[0] = f2bf((yv.x - mu) * inv);
        pk.u16[1] = f2bf((yv.y - mu) * inv);
        pk.u16[2] = f2bf((yv.z - mu) * inv);
        pk.u16[3] = f2bf((yv.w - mu) * inv);
        *reinterpret_cast<unsigned long long*>(
            reinterpret_cast<char*>(&h2B[0][0]) +
            rr * 256 + ((l * 8) ^ ((rr & 7) << 4))) = pk.u64;
    }
    __syncthreads();

    // --- M1: gs = silu(h2 @ W1.T + b1)  (8 waves x 4 col tiles) ---
    {
        s16x8 afr[4];
        #pragma unroll
        for (int ks = 0; ks < 4; ++ks) afr[ks] = lda_frag(&h2B[0][0], 256, ks, lane);
        const s16x8* Bp = reinterpret_cast<const s16x8*>(W1P);
        #pragma unroll
        for (int tt = 0; tt < 4; ++tt) {
            const int tile = wv * 4 + tt;
            f32x4 acc = {0.f, 0.f, 0.f, 0.f};
            #pragma unroll
            for (int ks = 0; ks < 4; ++ks) {
                const s16x8 b = Bp[(tile * 4 + ks) * 64 + lane];
                acc = __builtin_amdgcn_mfma_f32_16x16x32_bf16(afr[ks], b, acc, 0, 0, 0);
            }
            if (lane < 32) {
                const int c = tile * 16 + (lane & 15);
                const float bb = b1[c];
                #pragma unroll
                for (int i = 0; i < 4; ++i) {
                    const int m = ((lane >> 4) << 2) + i;  // 0..7
                    if (m < 4) {
                        const float g = acc[i] + bb;
                        const float sv = g / (1.0f + __expf(-g));
                        *reinterpret_cast<unsigned short*>(
                            reinterpret_cast<char*>(&gsB[0][0]) +
                            m * 1024 + ((c * 2) ^ ((m & 7) << 4))) = f2bf(sv);
                    }
                }
            }
        }
    }
    __syncthreads();

    // --- M2: out = x1 + gs @ W2.T + b2  (8 waves, K=512) ---
    {
        f32x4 acc = {0.f, 0.f, 0.f, 0.f};
        const s16x8* Bp = reinterpret_cast<const s16x8*>(W2P);
        #pragma unroll
        for (int ks = 0; ks < 16; ++ks) {
            const s16x8 a = lda_frag(&gsB[0][0], 1024, ks, lane);
            const s16x8 b = Bp[(wv * 16 + ks) * 64 + lane];
            acc = __builtin_amdgcn_mfma_f32_16x16x32_bf16(a, b, acc, 0, 0, 0);
        }
        if (lane < 32) {
            const int c = wv * 16 + (lane & 15);
            const float bb = b2[c];
            #pragma unroll
            for (int i = 0; i < 4; ++i) {
                const int m = ((lane >> 4) << 2) + i;   // 0..7
                if (m < 4)
                    out[(size_t)(row0 + m) * C_DIM + c] = ys[m][c] + bb + acc[i];
            }
        }
    }
}

// ---------------------------------------------------------------------------
extern "C" void kernel_launch(void* const* d_in, const int* in_sizes, int n_in,
                              void* d_out, int out_size, void* d_ws, size_t ws_size,
                              hipStream_t stream)
{
    const float* x    = (const float*)d_in[0];
    const float* pair = (const float*)d_in[1];
    const int*   bidx = (const int*)  d_in[2];
    const float* Wq   = (const float*)d_in[3];
    const float* Wk   = (const float*)d_in[4];
    const float* Wv   = (const float*)d_in[5];
    const float* Wb   = (const float*)d_in[6];
    const float* Wout = (const float*)d_in[7];
    const float* W1   = (const float*)d_in[8];
    const float* b1   = (const float*)d_in[9];
    const float* W2   = (const float*)d_in[10];
    const float* b2   = (const float*)d_in[11];
    float* out = (float*)d_out;

    char* ws = (char*)d_ws;
    float*          q     = (float*)ws;                               // 1 MB
    unsigned short* kb    = (unsigned short*)(ws + (1 << 20));        // 0.5 MB
    unsigned short* vb    = (unsigned short*)(ws + (1 << 20) + (1 << 19));
    unsigned short* WoutP = (unsigned short*)(ws + (2 << 20));        // 32 KB
    unsigned short* W1P   = (unsigned short*)(ws + (2 << 20) + (32 << 10));  // 128 KB
    unsigned short* W2P   = (unsigned short*)(ws + (2 << 20) + (160 << 10)); // 128 KB

    hipLaunchKernelGGL(ln_qkv_kernel, dim3(N_ATOMS / 16), dim3(512), 0, stream,
                       x, Wq, Wk, Wv, Wout, W1, W2, q, kb, vb, WoutP, W1P, W2P);
    hipLaunchKernelGGL(attn_mlp_kernel, dim3(N_ATOMS / 4), dim3(512), 0, stream,
                       q, kb, vb, pair, bidx, Wb, x, WoutP, W1P, b1, W2P, b2, out);
}